// Round 1
// baseline (871.886 us; speedup 1.0000x reference)
//
#include <hip/hip_runtime.h>
#include <hip/hip_bf16.h>

#define L_SEQ 4096
#define BATCH 8
#define DMODEL 1024
#define NHEAD 16
#define DHEAD 64
#define NSAMP 128

typedef __attribute__((ext_vector_type(8))) short short8;
typedef __attribute__((ext_vector_type(4))) float f32x4;

static __device__ __forceinline__ unsigned short f2bf(float f) {
    union { float f; unsigned int u; } x; x.f = f;
    unsigned int r = (x.u + 0x7fffu + ((x.u >> 16) & 1u)) >> 16;
    return (unsigned short)r;
}

// ---------------- elementwise f32 -> bf16 convert (float4 granularity) ------
__global__ void conv_bf16_kernel(const float* __restrict__ src,
                                 unsigned short* __restrict__ dst, int n4) {
    int idx = blockIdx.x * blockDim.x + threadIdx.x;
    if (idx < n4) {
        float4 v = ((const float4*)src)[idx];
        uint2 pk;
        pk.x = (unsigned)f2bf(v.x) | ((unsigned)f2bf(v.y) << 16);
        pk.y = (unsigned)f2bf(v.z) | ((unsigned)f2bf(v.w) << 16);
        ((uint2*)dst)[idx] = pk;
    }
}

// ---------------- gather rows of k/v by sampled_index (f32 out) -------------
// dst[s,b,d] = src[smp[s],b,d]; total4 = S*B*D/4, B*D/4 = 2048
__global__ void gather_kernel(const float* __restrict__ src,
                              const int* __restrict__ smp,
                              float* __restrict__ dst, int total4) {
    int idx = blockIdx.x * blockDim.x + threadIdx.x;
    if (idx < total4) {
        int s = idx >> 11;          // / (B*D/4)
        int rem = idx & 2047;
        ((float4*)dst)[idx] = ((const float4*)src)[(size_t)smp[s] * 2048 + rem];
    }
}

// ---------------- modify_key_length ----------------------------------------
__global__ void mkl_kernel(const int* __restrict__ smp,
                           const int* __restrict__ klen, int* __restrict__ mkl) {
    int b = threadIdx.x;
    if (b < BATCH) {
        int kl = klen[b];
        int c = 0;
        for (int s = 0; s < NSAMP; ++s) c += (smp[s] < kl) ? 1 : 0;
        mkl[b] = c;
    }
}

// ---------------- NT GEMM: C[M,N] = A[M,K] * B[N,K]^T + bias ----------------
// A: f32 (converted during staging) or bf16; B: bf16; C: bf16 or f32.
// Tile 128x128, BK=64, 256 threads (4 waves, 2x2 of 64x64).
template <bool A_IS_F32, bool OUT_F32>
__global__ __launch_bounds__(256) void gemm_nt(const void* __restrict__ Ap,
                                               const unsigned short* __restrict__ Bp,
                                               const float* __restrict__ bias,
                                               void* __restrict__ Cp,
                                               int M, int N, int K) {
    __shared__ __align__(16) unsigned short lA[128 * 64];
    __shared__ __align__(16) unsigned short lB[128 * 64];
    const int t = threadIdx.x;
    const int m0 = blockIdx.x * 128;
    const int n0 = blockIdx.y * 128;
    const int wave = t >> 6;
    const int lane = t & 63;
    const int l16 = lane & 15;
    const int quad = lane >> 4;
    const int wm = (wave >> 1) * 64;
    const int wn = (wave & 1) * 64;

    f32x4 acc[4][4];
    for (int i = 0; i < 4; ++i)
        for (int j = 0; j < 4; ++j)
            acc[i][j] = f32x4{0.f, 0.f, 0.f, 0.f};

    for (int k0 = 0; k0 < K; k0 += 64) {
        // stage A tile (128 rows x 64 k) into LDS as bf16
        if (A_IS_F32) {
            const float* A = (const float*)Ap;
            #pragma unroll
            for (int p = 0; p < 4; ++p) {
                int lin = (p * 256 + t) * 8;
                int row = lin >> 6, col = lin & 63;
                const float* g = A + (size_t)(m0 + row) * K + k0 + col;
                float4 v0 = *(const float4*)g;
                float4 v1 = *(const float4*)(g + 4);
                uint4 pk;
                pk.x = (unsigned)f2bf(v0.x) | ((unsigned)f2bf(v0.y) << 16);
                pk.y = (unsigned)f2bf(v0.z) | ((unsigned)f2bf(v0.w) << 16);
                pk.z = (unsigned)f2bf(v1.x) | ((unsigned)f2bf(v1.y) << 16);
                pk.w = (unsigned)f2bf(v1.z) | ((unsigned)f2bf(v1.w) << 16);
                *(uint4*)&lA[row * 64 + col] = pk;
            }
        } else {
            const unsigned short* A = (const unsigned short*)Ap;
            #pragma unroll
            for (int p = 0; p < 4; ++p) {
                int lin = (p * 256 + t) * 8;
                int row = lin >> 6, col = lin & 63;
                *(uint4*)&lA[row * 64 + col] =
                    *(const uint4*)(A + (size_t)(m0 + row) * K + k0 + col);
            }
        }
        // stage B tile (bf16)
        #pragma unroll
        for (int p = 0; p < 4; ++p) {
            int lin = (p * 256 + t) * 8;
            int row = lin >> 6, col = lin & 63;
            *(uint4*)&lB[row * 64 + col] =
                *(const uint4*)(Bp + (size_t)(n0 + row) * K + k0 + col);
        }
        __syncthreads();

        #pragma unroll
        for (int kk = 0; kk < 64; kk += 32) {
            short8 af[4], bfr[4];
            #pragma unroll
            for (int mt = 0; mt < 4; ++mt)
                af[mt] = *(const short8*)&lA[(wm + mt * 16 + l16) * 64 + kk + quad * 8];
            #pragma unroll
            for (int nt = 0; nt < 4; ++nt)
                bfr[nt] = *(const short8*)&lB[(wn + nt * 16 + l16) * 64 + kk + quad * 8];
            #pragma unroll
            for (int mt = 0; mt < 4; ++mt)
                #pragma unroll
                for (int nt = 0; nt < 4; ++nt)
                    acc[mt][nt] = __builtin_amdgcn_mfma_f32_16x16x32_bf16(
                        af[mt], bfr[nt], acc[mt][nt], 0, 0, 0);
        }
        __syncthreads();
    }

    // epilogue: C/D layout col=lane&15, row=quad*4+reg
    #pragma unroll
    for (int mt = 0; mt < 4; ++mt) {
        #pragma unroll
        for (int nt = 0; nt < 4; ++nt) {
            int col = n0 + wn + nt * 16 + l16;
            float bv = bias ? bias[col] : 0.f;
            #pragma unroll
            for (int r = 0; r < 4; ++r) {
                int row = m0 + wm + mt * 16 + quad * 4 + r;
                float val = acc[mt][nt][r] + bv;
                if (OUT_F32)
                    ((float*)Cp)[(size_t)row * N + col] = val;
                else
                    ((unsigned short*)Cp)[(size_t)row * N + col] = f2bf(val);
            }
        }
    }
}

// ---------------- fused attention ------------------------------------------
// grid: (L/64, B*H); 4 waves, each wave handles 16 query rows, full S=128.
__global__ __launch_bounds__(256) void attn_kernel(
    const unsigned short* __restrict__ qp,   // [L*B, D] bf16
    const unsigned short* __restrict__ kp,   // [S*B, D] bf16
    const unsigned short* __restrict__ vp,   // [S*B, D] bf16
    const int* __restrict__ smp_g,           // [S]
    const int* __restrict__ mkl_g,           // [B]
    unsigned short* __restrict__ ctx)        // [L*B, D] bf16
{
    __shared__ __align__(16) unsigned short vT[64 * 128];        // [d][s]
    __shared__ __align__(16) unsigned short pbuf[4][16 * 128];   // per-wave P
    __shared__ int smp_s[NSAMP];

    const int t = threadIdx.x;
    const int bh = blockIdx.y;
    const int b = bh >> 4, h = bh & 15;
    const int wave = t >> 6, lane = t & 63;
    const int l16 = lane & 15, quad = lane >> 4;
    const int l0 = blockIdx.x * 64 + wave * 16;
    const int mkl_b = mkl_g[b];

    // stage V^T: vT[d][s] = vp[(s*B+b)*D + h*64 + d]
    for (int idx = t; idx < 64 * 128; idx += 256) {
        int d = idx >> 7, s = idx & 127;
        vT[idx] = vp[((size_t)(s * BATCH + b)) * DMODEL + h * 64 + d];
    }
    if (t < NSAMP) smp_s[t] = smp_g[t];
    __syncthreads();

    // ---- QK^T: scores [16 rows x 128 samples] per wave ----
    short8 aq[2];
    {
        const unsigned short* qrow = qp + ((size_t)(l0 + l16) * BATCH + b) * DMODEL + h * 64;
        aq[0] = *(const short8*)&qrow[quad * 8];
        aq[1] = *(const short8*)&qrow[32 + quad * 8];
    }
    f32x4 sc[8];
    #pragma unroll
    for (int nt = 0; nt < 8; ++nt) sc[nt] = f32x4{0.f, 0.f, 0.f, 0.f};
    #pragma unroll
    for (int nt = 0; nt < 8; ++nt) {
        const unsigned short* krow =
            kp + ((size_t)((nt * 16 + l16) * BATCH + b)) * DMODEL + h * 64;
        short8 bk0 = *(const short8*)&krow[quad * 8];
        short8 bk1 = *(const short8*)&krow[32 + quad * 8];
        sc[nt] = __builtin_amdgcn_mfma_f32_16x16x32_bf16(aq[0], bk0, sc[nt], 0, 0, 0);
        sc[nt] = __builtin_amdgcn_mfma_f32_16x16x32_bf16(aq[1], bk1, sc[nt], 0, 0, 0);
    }

    // ---- scale + mask + softmax (rows = l0 + quad*4 + r) ----
    const float scale = 0.125f;  // 1/sqrt(64)
    #pragma unroll
    for (int nt = 0; nt < 8; ++nt) {
        int s = nt * 16 + l16;
        bool pad = (s >= mkl_b);
        int si = smp_s[s];
        #pragma unroll
        for (int r = 0; r < 4; ++r) {
            int lrow = l0 + quad * 4 + r;
            float v = sc[nt][r] * scale;
            if (pad || si > lrow) v = -INFINITY;
            sc[nt][r] = v;
        }
    }
    #pragma unroll
    for (int r = 0; r < 4; ++r) {
        float mx = sc[0][r];
        #pragma unroll
        for (int nt = 1; nt < 8; ++nt) mx = fmaxf(mx, sc[nt][r]);
        #pragma unroll
        for (int off = 1; off < 16; off <<= 1) mx = fmaxf(mx, __shfl_xor(mx, off));
        float sm = 0.f;
        #pragma unroll
        for (int nt = 0; nt < 8; ++nt) {
            float e = __expf(sc[nt][r] - mx);
            sc[nt][r] = e;
            sm += e;
        }
        #pragma unroll
        for (int off = 1; off < 16; off <<= 1) sm += __shfl_xor(sm, off);
        float inv = 1.0f / sm;   // >= 1 valid sample always (smp[0]=0, mkl>=1)
        #pragma unroll
        for (int nt = 0; nt < 8; ++nt) sc[nt][r] *= inv;
    }

    // ---- P: C-layout -> LDS -> A-layout ----
    #pragma unroll
    for (int nt = 0; nt < 8; ++nt)
        #pragma unroll
        for (int r = 0; r < 4; ++r)
            pbuf[wave][(quad * 4 + r) * 128 + nt * 16 + l16] = f2bf(sc[nt][r]);
    __syncthreads();

    // ---- P @ V^T: O [16 x 64] ----
    f32x4 oc[4];
    #pragma unroll
    for (int dt = 0; dt < 4; ++dt) oc[dt] = f32x4{0.f, 0.f, 0.f, 0.f};
    #pragma unroll
    for (int s0 = 0; s0 < 128; s0 += 32) {
        short8 ap = *(const short8*)&pbuf[wave][l16 * 128 + s0 + quad * 8];
        #pragma unroll
        for (int dt = 0; dt < 4; ++dt) {
            short8 bv = *(const short8*)&vT[(dt * 16 + l16) * 128 + s0 + quad * 8];
            oc[dt] = __builtin_amdgcn_mfma_f32_16x16x32_bf16(ap, bv, oc[dt], 0, 0, 0);
        }
    }

    // ---- write ctx (bf16, row-major [l*B+b][D]) ----
    #pragma unroll
    for (int dt = 0; dt < 4; ++dt)
        #pragma unroll
        for (int r = 0; r < 4; ++r) {
            int lrow = l0 + quad * 4 + r;
            ctx[((size_t)lrow * BATCH + b) * DMODEL + h * 64 + dt * 16 + l16] =
                f2bf(oc[dt][r]);
        }
}

// ---------------------------------------------------------------------------
extern "C" void kernel_launch(void* const* d_in, const int* in_sizes, int n_in,
                              void* d_out, int out_size, void* d_ws, size_t ws_size,
                              hipStream_t stream) {
    const float* q    = (const float*)d_in[0];
    const float* k    = (const float*)d_in[1];
    const float* v    = (const float*)d_in[2];
    const int*   klen = (const int*)d_in[3];
    const int*   smp  = (const int*)d_in[4];
    const float* ipw  = (const float*)d_in[5];
    const float* ipb  = (const float*)d_in[6];
    const float* ow   = (const float*)d_in[7];
    const float* ob   = (const float*)d_in[8];
    float* out = (float*)d_out;

    char* ws = (char*)d_ws;
    size_t off = 0;
    auto alloc = [&](size_t bytes) -> void* {
        void* p = ws + off;
        off += (bytes + 255) & ~(size_t)255;
        return p;
    };
    unsigned short* w_bf  = (unsigned short*)alloc((size_t)3 * 1024 * 1024 * 2);
    unsigned short* ow_bf = (unsigned short*)alloc((size_t)1024 * 1024 * 2);
    float*          ks_f  = (float*)alloc((size_t)NSAMP * BATCH * DMODEL * 4);
    float*          vs_f  = (float*)alloc((size_t)NSAMP * BATCH * DMODEL * 4);
    unsigned short* qp    = (unsigned short*)alloc((size_t)L_SEQ * BATCH * DMODEL * 2);
    unsigned short* kpp   = (unsigned short*)alloc((size_t)NSAMP * BATCH * DMODEL * 2);
    unsigned short* vpp   = (unsigned short*)alloc((size_t)NSAMP * BATCH * DMODEL * 2);
    unsigned short* ctx   = (unsigned short*)alloc((size_t)L_SEQ * BATCH * DMODEL * 2);
    int*            mkl   = (int*)alloc(256);

    // weights -> bf16
    conv_bf16_kernel<<<3072, 256, 0, stream>>>(ipw, w_bf, 3 * 1024 * 1024 / 4);
    conv_bf16_kernel<<<1024, 256, 0, stream>>>(ow, ow_bf, 1024 * 1024 / 4);
    // gather sampled k/v rows (f32)
    gather_kernel<<<1024, 256, 0, stream>>>(k, smp, ks_f, NSAMP * BATCH * DMODEL / 4);
    gather_kernel<<<1024, 256, 0, stream>>>(v, smp, vs_f, NSAMP * BATCH * DMODEL / 4);
    mkl_kernel<<<1, 64, 0, stream>>>(smp, klen, mkl);

    // projections (A f32 -> bf16 out)
    gemm_nt<true, false><<<dim3(256, 8), 256, 0, stream>>>(
        (const void*)q, w_bf, ipb, (void*)qp, L_SEQ * BATCH, DMODEL, DMODEL);
    gemm_nt<true, false><<<dim3(8, 8), 256, 0, stream>>>(
        (const void*)ks_f, w_bf + (size_t)1024 * 1024, ipb + 1024, (void*)kpp,
        NSAMP * BATCH, DMODEL, DMODEL);
    gemm_nt<true, false><<<dim3(8, 8), 256, 0, stream>>>(
        (const void*)vs_f, w_bf + (size_t)2 * 1024 * 1024, ipb + 2048, (void*)vpp,
        NSAMP * BATCH, DMODEL, DMODEL);

    // attention
    attn_kernel<<<dim3(L_SEQ / 64, BATCH * NHEAD), 256, 0, stream>>>(
        qp, kpp, vpp, smp, mkl, ctx);

    // output projection (A bf16 -> f32 out)
    gemm_nt<false, true><<<dim3(256, 8), 256, 0, stream>>>(
        (const void*)ctx, ow_bf, ob, (void*)out, L_SEQ * BATCH, DMODEL, DMODEL);
}

// Round 2
// 661.682 us; speedup vs baseline: 1.3177x; 1.3177x over previous
//
#include <hip/hip_runtime.h>
#include <hip/hip_bf16.h>

#define L_SEQ 4096
#define BATCH 8
#define DMODEL 1024
#define NHEAD 16
#define DHEAD 64
#define NSAMP 128

typedef __attribute__((ext_vector_type(8))) short short8;
typedef __attribute__((ext_vector_type(4))) float f32x4;

static __device__ __forceinline__ unsigned short f2bf(float f) {
    union { float f; unsigned int u; } x; x.f = f;
    unsigned int r = (x.u + 0x7fffu + ((x.u >> 16) & 1u)) >> 16;
    return (unsigned short)r;
}

// async global->LDS, 16B per lane; LDS dest must be wave-uniform-base + lane*16
static __device__ __forceinline__ void gld_lds16(const unsigned short* g,
                                                 unsigned short* l) {
    __builtin_amdgcn_global_load_lds(
        (const __attribute__((address_space(1))) void*)g,
        (__attribute__((address_space(3))) void*)l, 16, 0, 0);
}

// ---------------- elementwise f32 -> bf16 convert (float4 granularity) ------
__global__ void conv_bf16_kernel(const float* __restrict__ src,
                                 unsigned short* __restrict__ dst, int n4) {
    int idx = blockIdx.x * blockDim.x + threadIdx.x;
    if (idx < n4) {
        float4 v = ((const float4*)src)[idx];
        uint2 pk;
        pk.x = (unsigned)f2bf(v.x) | ((unsigned)f2bf(v.y) << 16);
        pk.y = (unsigned)f2bf(v.z) | ((unsigned)f2bf(v.w) << 16);
        ((uint2*)dst)[idx] = pk;
    }
}

// ---------------- gather rows of k/v by sampled_index -> bf16 ---------------
// dst[s,b,d] = bf16(src[smp[s],b,d]); chunks of 8 elems; B*D/8 = 1024
__global__ void gather_bf16_kernel(const float* __restrict__ src,
                                   const int* __restrict__ smp,
                                   unsigned short* __restrict__ dst, int total8) {
    int idx = blockIdx.x * blockDim.x + threadIdx.x;
    if (idx < total8) {
        int s = idx >> 10;
        int rem = idx & 1023;
        const float* g = src + (size_t)smp[s] * (BATCH * DMODEL) + rem * 8;
        float4 v0 = *(const float4*)g;
        float4 v1 = *(const float4*)(g + 4);
        uint4 pk;
        pk.x = (unsigned)f2bf(v0.x) | ((unsigned)f2bf(v0.y) << 16);
        pk.y = (unsigned)f2bf(v0.z) | ((unsigned)f2bf(v0.w) << 16);
        pk.z = (unsigned)f2bf(v1.x) | ((unsigned)f2bf(v1.y) << 16);
        pk.w = (unsigned)f2bf(v1.z) | ((unsigned)f2bf(v1.w) << 16);
        *(uint4*)&dst[(size_t)idx * 8] = pk;
    }
}

// ---------------- modify_key_length ----------------------------------------
__global__ void mkl_kernel(const int* __restrict__ smp,
                           const int* __restrict__ klen, int* __restrict__ mkl) {
    int b = threadIdx.x;
    if (b < BATCH) {
        int kl = klen[b];
        int c = 0;
        for (int s = 0; s < NSAMP; ++s) c += (smp[s] < kl) ? 1 : 0;
        mkl[b] = c;
    }
}

// ---------------- NT GEMM body: C[M,N] = A[M,K] * B[N,K]^T + bias ----------
// all-bf16 inputs, global_load_lds staging, tile 128x128, BK=64, 256 thr.
template <bool OUT_F32>
static __device__ __forceinline__ void gemm_body(
    const unsigned short* __restrict__ A, const unsigned short* __restrict__ Bw,
    const float* __restrict__ bias, void* __restrict__ Cp,
    int m0, int n0, int N, int K,
    unsigned short* lA, unsigned short* lB) {
    const int t = threadIdx.x;
    const int wave = t >> 6;
    const int lane = t & 63;
    const int l16 = lane & 15;
    const int quad = lane >> 4;
    const int wm = (wave >> 1) * 64;
    const int wn = (wave & 1) * 64;

    f32x4 acc[4][4];
    #pragma unroll
    for (int i = 0; i < 4; ++i)
        #pragma unroll
        for (int j = 0; j < 4; ++j)
            acc[i][j] = f32x4{0.f, 0.f, 0.f, 0.f};

    const int lin0 = t * 8;                 // per-thread element offset in tile
    const int wbase = (t & ~63) * 8;        // wave-uniform LDS base (elems)

    for (int k0 = 0; k0 < K; k0 += 64) {
        #pragma unroll
        for (int p = 0; p < 4; ++p) {
            int lin = p * 2048 + lin0;      // p*256*8
            int row = lin >> 6, col = lin & 63;
            gld_lds16(A + (size_t)(m0 + row) * K + k0 + col, lA + p * 2048 + wbase);
        }
        #pragma unroll
        for (int p = 0; p < 4; ++p) {
            int lin = p * 2048 + lin0;
            int row = lin >> 6, col = lin & 63;
            gld_lds16(Bw + (size_t)(n0 + row) * K + k0 + col, lB + p * 2048 + wbase);
        }
        __syncthreads();

        #pragma unroll
        for (int kk = 0; kk < 64; kk += 32) {
            short8 af[4], bfr[4];
            #pragma unroll
            for (int mt = 0; mt < 4; ++mt)
                af[mt] = *(const short8*)&lA[(wm + mt * 16 + l16) * 64 + kk + quad * 8];
            #pragma unroll
            for (int nt = 0; nt < 4; ++nt)
                bfr[nt] = *(const short8*)&lB[(wn + nt * 16 + l16) * 64 + kk + quad * 8];
            #pragma unroll
            for (int mt = 0; mt < 4; ++mt)
                #pragma unroll
                for (int nt = 0; nt < 4; ++nt)
                    acc[mt][nt] = __builtin_amdgcn_mfma_f32_16x16x32_bf16(
                        af[mt], bfr[nt], acc[mt][nt], 0, 0, 0);
        }
        __syncthreads();
    }

    // epilogue: C/D layout col=lane&15, row=quad*4+reg
    #pragma unroll
    for (int mt = 0; mt < 4; ++mt) {
        #pragma unroll
        for (int nt = 0; nt < 4; ++nt) {
            int col = n0 + wn + nt * 16 + l16;
            float bv = bias[col];
            #pragma unroll
            for (int r = 0; r < 4; ++r) {
                int row = m0 + wm + mt * 16 + quad * 4 + r;
                float val = acc[mt][nt][r] + bv;
                if (OUT_F32)
                    ((float*)Cp)[(size_t)row * N + col] = val;
                else
                    ((unsigned short*)Cp)[(size_t)row * N + col] = f2bf(val);
            }
        }
    }
}

__global__ __launch_bounds__(256) void gemm_bf16out(
    const unsigned short* __restrict__ A, const unsigned short* __restrict__ Bw,
    const float* __restrict__ bias, unsigned short* __restrict__ C, int N, int K) {
    __shared__ __align__(16) unsigned short lA[128 * 64];
    __shared__ __align__(16) unsigned short lB[128 * 64];
    gemm_body<false>(A, Bw, bias, C, blockIdx.x * 128, blockIdx.y * 128, N, K, lA, lB);
}

__global__ __launch_bounds__(256) void gemm_f32out(
    const unsigned short* __restrict__ A, const unsigned short* __restrict__ Bw,
    const float* __restrict__ bias, float* __restrict__ C, int N, int K) {
    __shared__ __align__(16) unsigned short lA[128 * 64];
    __shared__ __align__(16) unsigned short lB[128 * 64];
    gemm_body<true>(A, Bw, bias, C, blockIdx.x * 128, blockIdx.y * 128, N, K, lA, lB);
}

// fused K/V projection: z=0 -> kp, z=1 -> vp
__global__ __launch_bounds__(256) void gemm_kv(
    const unsigned short* __restrict__ Ak, const unsigned short* __restrict__ Av,
    const unsigned short* __restrict__ Bk, const unsigned short* __restrict__ Bv,
    const float* __restrict__ bk, const float* __restrict__ bv,
    unsigned short* __restrict__ Ck, unsigned short* __restrict__ Cv) {
    __shared__ __align__(16) unsigned short lA[128 * 64];
    __shared__ __align__(16) unsigned short lB[128 * 64];
    if (blockIdx.z == 0)
        gemm_body<false>(Ak, Bk, bk, Ck, blockIdx.x * 128, blockIdx.y * 128,
                         DMODEL, DMODEL, lA, lB);
    else
        gemm_body<false>(Av, Bv, bv, Cv, blockIdx.x * 128, blockIdx.y * 128,
                         DMODEL, DMODEL, lA, lB);
}

// ---------------- fused attention ------------------------------------------
// grid: (L/256, B*H); 4 waves, each wave handles 64 query rows (4 tiles of 16).
// K staged padded (stride 72), V^T padded (stride 136) -> 2-way banks (free).
#define KST 72
#define VST 136
__global__ __launch_bounds__(256) void attn_kernel(
    const unsigned short* __restrict__ qp,   // [L*B, D] bf16
    const unsigned short* __restrict__ kp,   // [S*B, D] bf16
    const unsigned short* __restrict__ vp,   // [S*B, D] bf16
    const int* __restrict__ smp_g,           // [S]
    const int* __restrict__ mkl_g,           // [B]
    unsigned short* __restrict__ ctx)        // [L*B, D] bf16
{
    __shared__ __align__(16) unsigned short kbuf[NSAMP * KST];   // [s][d] padded
    __shared__ __align__(16) unsigned short vT[64 * VST];        // [d][s] padded
    __shared__ __align__(16) unsigned short pbuf[4][16 * VST];   // per-wave P
    __shared__ int smp_s[NSAMP];

    const int t = threadIdx.x;
    const int b = blockIdx.y >> 4, h = blockIdx.y & 15;
    const int wave = t >> 6, lane = t & 63;
    const int l16 = lane & 15, quad = lane >> 4;
    const int Lbase = blockIdx.x * 256;
    const int mkl_b = mkl_g[b];

    // stage K tile: 128 rows x 64 d, 16B chunks, coalesced-by-row
    #pragma unroll
    for (int p = 0; p < 4; ++p) {
        int c = p * 256 + t;                  // 0..1023 chunks
        int s = c >> 3, d0 = (c & 7) * 8;
        *(uint4*)&kbuf[s * KST + d0] =
            *(const uint4*)&kp[((size_t)(s * BATCH + b)) * DMODEL + h * 64 + d0];
    }
    // stage V^T: read 16B chunks of vp, scatter 8 scalar LDS writes
    #pragma unroll
    for (int p = 0; p < 4; ++p) {
        int c = p * 256 + t;
        int s = c >> 3, d0 = (c & 7) * 8;
        uint4 pk = *(const uint4*)&vp[((size_t)(s * BATCH + b)) * DMODEL + h * 64 + d0];
        const unsigned short* e = (const unsigned short*)&pk;
        #pragma unroll
        for (int j = 0; j < 8; ++j) vT[(d0 + j) * VST + s] = e[j];
    }
    if (t < NSAMP) smp_s[t] = smp_g[t];
    __syncthreads();

    // hoist K fragments (shared by all 4 Q-tiles of this wave)
    short8 kf[8][2];
    #pragma unroll
    for (int nt = 0; nt < 8; ++nt) {
        kf[nt][0] = *(const short8*)&kbuf[(nt * 16 + l16) * KST + quad * 8];
        kf[nt][1] = *(const short8*)&kbuf[(nt * 16 + l16) * KST + 32 + quad * 8];
    }

    const float scale = 0.125f;  // 1/sqrt(64)

    for (int qt = 0; qt < 4; ++qt) {
        const int l0 = Lbase + wave * 64 + qt * 16;

        // Q fragments
        short8 aq0, aq1;
        {
            const unsigned short* qrow =
                qp + ((size_t)(l0 + l16) * BATCH + b) * DMODEL + h * 64;
            aq0 = *(const short8*)&qrow[quad * 8];
            aq1 = *(const short8*)&qrow[32 + quad * 8];
        }

        // QK^T
        f32x4 sc[8];
        #pragma unroll
        for (int nt = 0; nt < 8; ++nt) sc[nt] = f32x4{0.f, 0.f, 0.f, 0.f};
        #pragma unroll
        for (int nt = 0; nt < 8; ++nt) {
            sc[nt] = __builtin_amdgcn_mfma_f32_16x16x32_bf16(aq0, kf[nt][0], sc[nt], 0, 0, 0);
            sc[nt] = __builtin_amdgcn_mfma_f32_16x16x32_bf16(aq1, kf[nt][1], sc[nt], 0, 0, 0);
        }

        // scale + mask + softmax (rows = l0 + quad*4 + r)
        #pragma unroll
        for (int nt = 0; nt < 8; ++nt) {
            int s = nt * 16 + l16;
            bool pad = (s >= mkl_b);
            int si = smp_s[s];
            #pragma unroll
            for (int r = 0; r < 4; ++r) {
                int lrow = l0 + quad * 4 + r;
                float v = sc[nt][r] * scale;
                if (pad || si > lrow) v = -INFINITY;
                sc[nt][r] = v;
            }
        }
        #pragma unroll
        for (int r = 0; r < 4; ++r) {
            float mx = sc[0][r];
            #pragma unroll
            for (int nt = 1; nt < 8; ++nt) mx = fmaxf(mx, sc[nt][r]);
            #pragma unroll
            for (int off = 1; off < 16; off <<= 1) mx = fmaxf(mx, __shfl_xor(mx, off));
            float sm = 0.f;
            #pragma unroll
            for (int nt = 0; nt < 8; ++nt) {
                float e = __expf(sc[nt][r] - mx);
                sc[nt][r] = e;
                sm += e;
            }
            #pragma unroll
            for (int off = 1; off < 16; off <<= 1) sm += __shfl_xor(sm, off);
            float inv = 1.0f / sm;   // >=1 valid sample (smp[0]=0, mkl>=1)
            #pragma unroll
            for (int nt = 0; nt < 8; ++nt) sc[nt][r] *= inv;
        }

        // P: C-layout -> per-wave LDS -> A-layout (wave-local, no barrier)
        #pragma unroll
        for (int nt = 0; nt < 8; ++nt)
            #pragma unroll
            for (int r = 0; r < 4; ++r)
                pbuf[wave][(quad * 4 + r) * VST + nt * 16 + l16] = f2bf(sc[nt][r]);

        // P @ V^T
        f32x4 oc[4];
        #pragma unroll
        for (int dt = 0; dt < 4; ++dt) oc[dt] = f32x4{0.f, 0.f, 0.f, 0.f};
        #pragma unroll
        for (int s0 = 0; s0 < 128; s0 += 32) {
            short8 ap = *(const short8*)&pbuf[wave][l16 * VST + s0 + quad * 8];
            #pragma unroll
            for (int dt = 0; dt < 4; ++dt) {
                short8 bv = *(const short8*)&vT[(dt * 16 + l16) * VST + s0 + quad * 8];
                oc[dt] = __builtin_amdgcn_mfma_f32_16x16x32_bf16(ap, bv, oc[dt], 0, 0, 0);
            }
        }

        // write ctx
        #pragma unroll
        for (int dt = 0; dt < 4; ++dt)
            #pragma unroll
            for (int r = 0; r < 4; ++r) {
                int lrow = l0 + quad * 4 + r;
                ctx[((size_t)lrow * BATCH + b) * DMODEL + h * 64 + dt * 16 + l16] =
                    f2bf(oc[dt][r]);
            }
    }
}

// ---------------------------------------------------------------------------
extern "C" void kernel_launch(void* const* d_in, const int* in_sizes, int n_in,
                              void* d_out, int out_size, void* d_ws, size_t ws_size,
                              hipStream_t stream) {
    const float* q    = (const float*)d_in[0];
    const float* k    = (const float*)d_in[1];
    const float* v    = (const float*)d_in[2];
    const int*   klen = (const int*)d_in[3];
    const int*   smp  = (const int*)d_in[4];
    const float* ipw  = (const float*)d_in[5];
    const float* ipb  = (const float*)d_in[6];
    const float* ow   = (const float*)d_in[7];
    const float* ob   = (const float*)d_in[8];
    float* out = (float*)d_out;

    char* ws = (char*)d_ws;
    size_t off = 0;
    auto alloc = [&](size_t bytes) -> void* {
        void* p = ws + off;
        off += (bytes + 255) & ~(size_t)255;
        return p;
    };
    unsigned short* w_bf  = (unsigned short*)alloc((size_t)3 * 1024 * 1024 * 2);
    unsigned short* ow_bf = (unsigned short*)alloc((size_t)1024 * 1024 * 2);
    unsigned short* ks_bf = (unsigned short*)alloc((size_t)NSAMP * BATCH * DMODEL * 2);
    unsigned short* vs_bf = (unsigned short*)alloc((size_t)NSAMP * BATCH * DMODEL * 2);
    unsigned short* q_bf  = (unsigned short*)alloc((size_t)L_SEQ * BATCH * DMODEL * 2);
    unsigned short* qp    = (unsigned short*)alloc((size_t)L_SEQ * BATCH * DMODEL * 2);
    unsigned short* kpp   = (unsigned short*)alloc((size_t)NSAMP * BATCH * DMODEL * 2);
    unsigned short* vpp   = (unsigned short*)alloc((size_t)NSAMP * BATCH * DMODEL * 2);
    int*            mkl   = (int*)alloc(256);
    // ctx aliases q_bf (q_bf dead after qp GEMM; attn runs strictly after)
    unsigned short* ctx = q_bf;

    // conversions
    conv_bf16_kernel<<<32768, 256, 0, stream>>>(q, q_bf, L_SEQ * BATCH * DMODEL / 4);
    conv_bf16_kernel<<<3072, 256, 0, stream>>>(ipw, w_bf, 3 * 1024 * 1024 / 4);
    conv_bf16_kernel<<<1024, 256, 0, stream>>>(ow, ow_bf, 1024 * 1024 / 4);
    // gathers (f32 -> bf16)
    gather_bf16_kernel<<<512, 256, 0, stream>>>(k, smp, ks_bf, NSAMP * BATCH * DMODEL / 8);
    gather_bf16_kernel<<<512, 256, 0, stream>>>(v, smp, vs_bf, NSAMP * BATCH * DMODEL / 8);
    mkl_kernel<<<1, 64, 0, stream>>>(smp, klen, mkl);

    // Q projection: [32768,1024] x [1024,1024]^T
    gemm_bf16out<<<dim3(256, 8), 256, 0, stream>>>(q_bf, w_bf, ipb, qp, DMODEL, DMODEL);
    // K/V projections fused (z)
    gemm_kv<<<dim3(8, 8, 2), 256, 0, stream>>>(
        ks_bf, vs_bf, w_bf + (size_t)1024 * 1024, w_bf + (size_t)2 * 1024 * 1024,
        ipb + 1024, ipb + 2048, kpp, vpp);

    // attention
    attn_kernel<<<dim3(L_SEQ / 256, BATCH * NHEAD), 256, 0, stream>>>(
        qp, kpp, vpp, smp, mkl, ctx);

    // output projection -> f32
    gemm_f32out<<<dim3(256, 8), 256, 0, stream>>>(ctx, ow_bf, ob, out, DMODEL, DMODEL);
}